// Round 3
// baseline (273.080 us; speedup 1.0000x reference)
//
#include <hip/hip_runtime.h>
#include <stdint.h>

// F=16, N=8192, D=64, K=512. fp32 in/out. Bit-exact numpy-fp32 emulation.
// R15: FMA approximate pre-pass + gap gate + IN-BLOCK cooperative exact rescan.
//   R13/R14 failed with bit-identical errors across a 5x THRESH change and a merge
//   rewrite -> bug isolated to the cross-kernel deferral machinery / new data paths.
//   R15 deletes all of it: no list/cnt/fixup kernel; flagged points are re-scanned
//   exactly (R7 chain, first-index u64-key argmin) by the whole block inline.
//   s_load reverts to the R12-proven offsets (0x0..0x100); ws layout reverts to R12.
// Gate math: s_approx = -2*acc, |s_approx - s_exact| <= ~4e-4 worst case;
// merged top-2 gap > THRESH=1e-2 (>=12x margin) proves the approx winner is the
// unique exact argmin (first-index moot). Otherwise: exact rescan.
#define F_ 16
#define N_ 8192
#define D_ 64
#define K_ 512
#define WROW 68                      // floats per padded row: [w[0..63], wsq, pad x3]
#define THRESH_ 1e-2f                // s-space gap gate; >=12x the 2*delta bound

typedef __attribute__((ext_vector_type(16))) float f16v;
typedef unsigned long long ull;

// -------- prep: row transpose + embedded seq-d wsq (R12 semantics, wider grid) ----
// grid = F*K/64 blocks x 64 threads; prefetch all 64 strided loads, then serial chain.
__global__ __launch_bounds__(64) void vq_prep(const float* __restrict__ w,
                                              float* __restrict__ wt) {
    #pragma clang fp contract(off)
    int i = blockIdx.x * 64 + threadIdx.x;    // one thread per (f,k)
    int f = i >> 9;
    int k = i & (K_ - 1);
    const float* wf = w + (size_t)f * D_ * K_ + k;
    float v[D_];
    #pragma unroll
    for (int d = 0; d < D_; ++d) v[d] = wf[(size_t)d * K_];   // coalesced over k
    float* dst = wt + ((size_t)f * K_ + k) * WROW;
    float s = 0.f;
    #pragma unroll
    for (int d = 0; d < D_; ++d) {
        dst[d] = v[d];
        s = __fadd_rn(s, __fmul_rn(v[d], v[d]));  // numpy seq-d reduce (R7-verified)
    }
    dst[D_] = s;                              // wsq embedded at row[64] (R12-proven)
}

// shared epilogue: verbatim R12 ops (row copy, STE, f64 loss accumulation)
__device__ __forceinline__ void write_point(const float* __restrict__ wtf, int bestk,
                                            const float* xr_, int point,
                                            float* __restrict__ out, double* lsum) {
    #pragma clang fp contract(off)
    const float* qrow = wtf + (size_t)bestk * WROW;  // exact copies of w values
    float4* ov = (float4*)(out + (size_t)point * D_);
    #pragma unroll
    for (int i = 0; i < D_ / 4; ++i) {
        float4 q = ((const float4*)qrow)[i];
        float e0 = __fsub_rn(q.x, xr_[4*i+0]), e1 = __fsub_rn(q.y, xr_[4*i+1]);
        float e2 = __fsub_rn(q.z, xr_[4*i+2]), e3 = __fsub_rn(q.w, xr_[4*i+3]);
        float4 o;
        o.x = __fadd_rn(xr_[4*i+0], e0); o.y = __fadd_rn(xr_[4*i+1], e1);
        o.z = __fadd_rn(xr_[4*i+2], e2); o.w = __fadd_rn(xr_[4*i+3], e3);
        ov[i] = o;
        *lsum += (double)__fmul_rn(e0, e0);
        *lsum += (double)__fmul_rn(e1, e1);
        *lsum += (double)__fmul_rn(e2, e2);
        *lsum += (double)__fmul_rn(e3, e3);
    }
}

// -------- main: block = 64 points x 4 K-quarters (4 waves); lane = point --------
__global__ __launch_bounds__(256) void vq_main(const float* __restrict__ x,
                                               const float* __restrict__ wt,
                                               float* __restrict__ out,
                                               double* __restrict__ lacc) {
    #pragma clang fp contract(off)
    __shared__ ull keysA[4][64];     // per-quarter best key  (accbits<<32 | idx)
    __shared__ ull keysB[4][64];     // per-quarter second key
    __shared__ ull rk[256];          // rescan reduction tree
    __shared__ float xrow[D_];       // rescan: flagged point's x row
    __shared__ float xsqs[64];       // per-point xsq (bitwise, from wave 0)
    __shared__ ull fmask_lds;        // flagged-point mask

    const int tid  = threadIdx.x;
    const int kq   = tid >> 6;                       // K-quarter 0..3
    const int lane = tid & 63;
    const int point = blockIdx.x * 64 + lane;
    const int f     = blockIdx.x >> 7;               // 128 blocks per f; uniform

    // x[point][:] -> lane-private registers (each wave loads the same 64 points)
    float xr[D_];
    {
        const float4* xv = (const float4*)(x + (size_t)point * D_);
        #pragma unroll
        for (int i = 0; i < D_ / 4; ++i) {
            float4 u = xv[i];
            xr[4*i+0] = u.x; xr[4*i+1] = u.y; xr[4*i+2] = u.z; xr[4*i+3] = u.w;
        }
    }

    // xsq: numpy pairwise-8 tree (R7-verified bit-exact)
    float xsq;
    {
        float r[8];
        #pragma unroll
        for (int j = 0; j < 8; ++j) r[j] = __fmul_rn(xr[j], xr[j]);
        #pragma unroll
        for (int i = 8; i < 64; i += 8)
            #pragma unroll
            for (int j = 0; j < 8; ++j)
                r[j] = __fadd_rn(r[j], __fmul_rn(xr[i+j], xr[i+j]));
        float c01 = __fadd_rn(r[0], r[1]), c23 = __fadd_rn(r[2], r[3]);
        float c45 = __fadd_rn(r[4], r[5]), c67 = __fadd_rn(r[6], r[7]);
        xsq = __fadd_rn(__fadd_rn(c01, c23), __fadd_rn(c45, c67));
    }

    const float* wtf = wt + (size_t)f * K_ * WROW;
    const int j0 = kq << 7;                          // 128 codes per quarter

    // Wave-uniform byte base, laundered to SGPRs (R10/R12-proven pattern).
    uint64_t a = (uint64_t)(wtf + (size_t)j0 * WROW);
    uint32_t alo = __builtin_amdgcn_readfirstlane((uint32_t)a);
    uint32_t ahi = __builtin_amdgcn_readfirstlane((uint32_t)(a >> 32));
    const uint64_t ubase = ((uint64_t)ahi << 32) | alo;

    // Approximate pass: acc = fl(-xsq/2 + fl(-0.5*wsq)) then 64 fused FMAs.
    // acc = -s/2 < 0 always, so more-negative acc <=> larger uint bits:
    // u64-key MIN == (max acc == min s, then min idx) — R12's proven ordering trick.
    const float nxsqh = __fmul_rn(-0.5f, xsq);
    ull k1q = ~0ull, k2q = ~0ull;                    // two smallest keys this quarter

    #pragma clang loop unroll(disable)
    for (int jj = 0; jj < 128; ++jj) {
        uint64_t ua = ubase + (uint64_t)jj * (WROW * 4);   // uniform scalar arithmetic
        f16v wa, wb, wc, wd;
        float wsqj;
        asm volatile("s_load_dwordx16 %0, %5, 0x0\n\t"
                     "s_load_dwordx16 %1, %5, 0x40\n\t"
                     "s_load_dwordx16 %2, %5, 0x80\n\t"
                     "s_load_dwordx16 %3, %5, 0xc0\n\t"
                     "s_load_dword    %4, %5, 0x100\n\t"   // R12-proven offsets
                     "s_waitcnt lgkmcnt(0)"
                     : "=&s"(wa), "=&s"(wb), "=&s"(wc), "=&s"(wd), "=&s"(wsqj)
                     : "s"(ua));

        float acc = __fadd_rn(nxsqh, __fmul_rn(-0.5f, wsqj));  // exact halving
        #pragma unroll
        for (int i = 0; i < 16; ++i) acc = __fmaf_rn(xr[i],      wa[i], acc);
        #pragma unroll
        for (int i = 0; i < 16; ++i) acc = __fmaf_rn(xr[16 + i], wb[i], acc);
        #pragma unroll
        for (int i = 0; i < 16; ++i) acc = __fmaf_rn(xr[32 + i], wc[i], acc);
        #pragma unroll
        for (int i = 0; i < 16; ++i) acc = __fmaf_rn(xr[48 + i], wd[i], acc);

        // keep the two smallest keys (keys unique via idx bits)
        ull key = ((ull)__float_as_uint(acc) << 32) | (unsigned int)(j0 + jj);
        bool b1 = key < k1q;
        bool b2 = key < k2q;
        ull nk2 = b1 ? k1q : (b2 ? key : k2q);
        k1q = b1 ? key : k1q;
        k2q = nk2;
    }

    keysA[kq][lane] = k1q;
    keysB[kq][lane] = k2q;
    __syncthreads();

    // -------- wave 0: top-2-of-8 merge + gap gate; fast path writes out now ------
    double lsum = 0.0;
    if (tid < 64) {
        ull kb = keysA[0][lane];
        #pragma unroll
        for (int q = 1; q < 4; ++q) {
            ull t = keysA[q][lane];
            if (t < kb) kb = t;
        }
        ull ks = ~0ull;
        #pragma unroll
        for (int q = 0; q < 4; ++q) {
            ull ta = keysA[q][lane];
            ull cand = (ta == kb) ? keysB[q][lane] : ta;
            if (cand < ks) ks = cand;
        }
        float m1  = __uint_as_float((unsigned int)(kb >> 32));
        float m2v = __uint_as_float((unsigned int)(ks >> 32));
        // s-space gap = 2*(m1-m2); small gap -> exact winner not provable -> rescan
        bool need = (__fmul_rn(2.0f, __fsub_rn(m1, m2v)) <= THRESH_);
        ull bm = __ballot(need);
        if (lane == 0) fmask_lds = bm;
        xsqs[lane] = xsq;
        if (!need)
            write_point(wtf, (int)(kb & 0xffffffffu), xr, point, out, &lsum);
    }
    __syncthreads();

    // -------- cooperative exact rescan of flagged points (R7 chain, first-index) --
    ull fmask = fmask_lds;                           // uniform across block
    while (fmask) {
        const int pl = (int)__builtin_ctzll(fmask);
        fmask &= fmask - 1;
        const int pp = blockIdx.x * 64 + pl;
        if (tid < 64) xrow[tid] = x[(size_t)pp * D_ + tid];
        __syncthreads();
        const float pxsq = xsqs[pl];                 // bitwise-identical xsq

        ull mykey = ~0ull;                           // 2 codes per thread: tid, tid+256
        #pragma clang loop unroll(disable)
        for (int t = 0; t < 2; ++t) {
            const int j = tid + (t << 8);
            const float* row = wtf + (size_t)j * WROW;
            float acc = 0.f;
            #pragma clang loop unroll(disable)
            for (int i = 0; i < 16; ++i) {           // d ascending: exact R7 chain
                float4 q = ((const float4*)row)[i];
                acc = __fadd_rn(acc, __fmul_rn(xrow[4*i+0], q.x));
                acc = __fadd_rn(acc, __fmul_rn(xrow[4*i+1], q.y));
                acc = __fadd_rn(acc, __fmul_rn(xrow[4*i+2], q.z));
                acc = __fadd_rn(acc, __fmul_rn(xrow[4*i+3], q.w));
            }
            float s = __fadd_rn(__fsub_rn(pxsq, __fmul_rn(2.0f, acc)), row[D_]);
            ull key = ((ull)__float_as_uint(s) << 32) | (unsigned int)j;  // s > 0
            if (key < mykey) mykey = key;
        }
        rk[tid] = mykey;
        __syncthreads();
        #pragma unroll
        for (int sft = 128; sft >= 1; sft >>= 1) {   // u64-key min tree: first-index
            if (tid < sft) {
                ull o = rk[tid + sft];
                if (o < rk[tid]) rk[tid] = o;
            }
            __syncthreads();
        }
        if (tid == pl)                               // owning wave-0 lane has xr
            write_point(wtf, (int)(rk[0] & 0xffffffffu), xr, pp, out, &lsum);
        __syncthreads();                             // protect rk/xrow for next iter
    }

    // wave reduce (non-contributing lanes hold 0), single atomic from tid 0
    #pragma unroll
    for (int off = 32; off >= 1; off >>= 1)
        lsum += __shfl_down(lsum, off);
    if (tid == 0)
        atomicAdd(lacc, lsum);
}

// loss = fl(m + fl(0.25*m)), m = fp32(mean) — R7-verified
__global__ void vq_finalize(const double* __restrict__ lacc, float* __restrict__ out) {
    #pragma clang fp contract(off)
    double m64 = lacc[0] / (double)((size_t)F_ * N_ * D_);
    float m = (float)m64;
    out[0] = __fadd_rn(m, __fmul_rn(0.25f, m));
}

extern "C" void kernel_launch(void* const* d_in, const int* in_sizes, int n_in,
                              void* d_out, int out_size, void* d_ws, size_t ws_size,
                              hipStream_t stream) {
    const float* x = (const float*)d_in[0];   // fp32 [F,N,D]
    const float* w = (const float*)d_in[1];   // fp32 [F,D,K]
    if (in_sizes[0] == F_ * D_ * K_ && in_sizes[1] == F_ * N_ * D_) {
        x = (const float*)d_in[1];
        w = (const float*)d_in[0];
    }
    float* out = (float*)d_out;               // fp32 [F*N*D + 1]

    // ws: wt fp32 [F*K*WROW] (~2.23 MB, padded rows w/ embedded wsq) | lacc f64
    // (identical to the R12-proven layout; nothing else lives in ws)
    float*  wt   = (float*)d_ws;
    double* lacc = (double*)((char*)d_ws + sizeof(float) * (size_t)F_ * K_ * WROW);

    hipMemsetAsync(lacc, 0, sizeof(double), stream);
    vq_prep<<<(F_ * K_) / 64, 64, 0, stream>>>(w, wt);
    vq_main<<<(F_ * N_) / 64, 256, 0, stream>>>(x, wt, out, lacc);
    vq_finalize<<<1, 1, 0, stream>>>(lacc, out + (size_t)F_ * N_ * D_);
}